// Round 14
// baseline (3570.647 us; speedup 1.0000x reference)
//
#include <hip/hip_runtime.h>
#include <math.h>

// RepCodec: Vocos encoder + factorized VQ.
// GEMMs on MFMA via fp16 two-term split (hi+lo), 3 passes: hh + hl + lh.
// Round 14: on-the-fly weight split inside GEMM staging (deletes 12 split
// launches; bit-identical hi/lo), fused final-LN+vq_ze. Core loops frozen.

typedef _Float16 h8_t __attribute__((ext_vector_type(8)));
typedef _Float16 h4_t __attribute__((ext_vector_type(4)));
typedef float f4_t __attribute__((ext_vector_type(4)));

__device__ __forceinline__ float gelu_exact(float x){
  return 0.5f * x * (1.0f + erff(x * 0.70710678118654752f));
}

__device__ __forceinline__ void split4(const float4& a, h4_t& hi, h4_t& lo){
  float f[4] = {a.x,a.y,a.z,a.w};
  #pragma unroll
  for (int t=0;t<4;t++){
    _Float16 hh = (_Float16)f[t];
    hi[t] = hh;
    lo[t] = (_Float16)(f[t] - (float)hh);
  }
}

__device__ __forceinline__ void split8(const float4& a, const float4& b, h8_t& hi, h8_t& lo){
  float f[8] = {a.x,a.y,a.z,a.w,b.x,b.y,b.z,b.w};
  #pragma unroll
  for (int t=0;t<8;t++){
    _Float16 hh = (_Float16)f[t];
    hi[t] = hh;
    lo[t] = (_Float16)(f[t] - (float)hh);
  }
}

// LDS slot swizzle (r3/r6-measured: SQ_LDS_BANK_CONFLICT == 0 with tid>>2 staging).
__device__ __forceinline__ int swz(int row, int kg){
  return row*32 + ((kg ^ ((row>>1)&3))<<3);
}

// XCD-aware bijective block swizzle (grids with nwg%8==0)
__device__ __forceinline__ void xcd_remap(int& bx, int& by){
  const int gx = gridDim.x;
  const int nwg = gx * gridDim.y;
  int bid = by*gx + bx;
  if ((nwg & 7) == 0){
    bid = (bid & 7)*(nwg >> 3) + (bid >> 3);
    bx = bid % gx; by = bid / gx;
  }
}

// ---------------- prep kernels ----------------

__global__ __launch_bounds__(256) void prep_wk_split(const float* __restrict__ w,
                                                     _Float16* __restrict__ wh,
                                                     _Float16* __restrict__ wl){
  int i = blockIdx.x*256 + threadIdx.x;
  if (i >= 384*1024) return;
  int d = i >> 10, c = i & 1023;
  #pragma unroll
  for (int k=0;k<7;k++){
    float v = w[(size_t)d*(1024*7) + (size_t)c*7 + k];
    _Float16 hh = (_Float16)v;
    wh[(size_t)k*393216 + i] = hh;
    wl[(size_t)k*393216 + i] = (_Float16)(v - (float)hh);
  }
}

// Merged VQ prep: blocks 0-11 -> cw fold (+cbias on block 0); blocks 12-43 -> cbn.
__global__ __launch_bounds__(256) void prep_vq(const float* __restrict__ viw, const float* __restrict__ ow,
                                               const float* __restrict__ vib, const float* __restrict__ ob,
                                               const float* __restrict__ cb,
                                               float* __restrict__ cw, float* __restrict__ cbias,
                                               float* __restrict__ cbn){
  const int blk = blockIdx.x, tid = threadIdx.x;
  if (blk < 12){
    int i = blk*256 + tid;
    if (i < 3072){
      int c = i / 384, d = i - c*384;
      float acc = 0.f;
      for (int h=0; h<1024; ++h)
        acc = fmaf(viw[c*1024+h], ow[(size_t)h*384 + d], acc);
      cw[i] = acc;
    }
    if (blk == 0 && tid < 8){
      int c = tid;
      float acc = vib[c];
      for (int h=0; h<1024; ++h) acc = fmaf(viw[c*1024+h], ob[h], acc);
      cbias[c] = acc;
    }
  } else {
    int e = (blk-12)*256 + tid;
    float v[8], s = 0.f;
    #pragma unroll
    for (int cd=0; cd<8; ++cd){ v[cd] = cb[(size_t)e*8+cd]; s += v[cd]*v[cd]; }
    float inv = 1.0f / fmaxf(sqrtf(s), 1e-12f);
    #pragma unroll
    for (int cd=0; cd<8; ++cd) cbn[(size_t)e*8+cd] = v[cd]*inv;
  }
}

__global__ __launch_bounds__(256) void split_one(const float* __restrict__ a,
                                                 _Float16* __restrict__ ah, _Float16* __restrict__ al,
                                                 int n4){
  int i = blockIdx.x*256 + threadIdx.x;
  if (i >= n4) return;
  h4_t hi, lo;
  float4 va = ((const float4*)a)[i];
  split4(va, hi, lo);
  ((h4_t*)ah)[i] = hi; ((h4_t*)al)[i] = lo;
}

// ---------------- gemm_n64 (r6-proven core): BM=128, BN=64, BK=32; fp32 B split on the fly ----
// C(fp32) += gamma * (acc + bias?)
__global__ __launch_bounds__(256,2) void gemm_n64(
    const _Float16* __restrict__ Ah, const _Float16* __restrict__ Al, int lda,
    const float* __restrict__ W, int ldb,
    const float* __restrict__ bias, const float* __restrict__ gamma,
    float* __restrict__ C, int ldc, int K)
{
  __shared__ _Float16 AsH[4096], AsL[4096];
  __shared__ _Float16 BsH[2048], BsL[2048];
  const int tid = threadIdx.x;
  int bx = blockIdx.x, by = blockIdx.y;
  xcd_remap(bx, by);
  const int m0 = by*128, n0 = bx*64;
  const int srow = tid>>2, kgs = tid&3, koff = kgs*8;
  const _Float16* pAh = Ah + (size_t)(m0+srow)*lda + koff;
  const _Float16* pAl = Al + (size_t)(m0+srow)*lda + koff;
  const float*    pB  = W  + (size_t)(n0+srow)*ldb + koff;
  const int sA0 = swz(srow, kgs), sA1 = swz(srow+64, kgs);
  const int lane = tid & 63, wid = tid >> 6;
  const int wm = (wid>>1)*64, wn = (wid&1)*32;
  const int fr = lane & 15, kg = lane >> 4;
  f4_t acc[4][2] = {};
  h8_t rah0 = *(const h8_t*)(pAh);
  h8_t rah1 = *(const h8_t*)(pAh + (size_t)64*lda);
  h8_t ral0 = *(const h8_t*)(pAl);
  h8_t ral1 = *(const h8_t*)(pAl + (size_t)64*lda);
  float4 rb0 = *(const float4*)(pB);
  float4 rb1 = *(const float4*)(pB + 4);
  for (int k0 = 0; k0 < K; k0 += 32){
    h8_t rbh0, rbl0;
    split8(rb0, rb1, rbh0, rbl0);
    __syncthreads();
    *(h8_t*)(AsH + sA0) = rah0; *(h8_t*)(AsL + sA0) = ral0;
    *(h8_t*)(AsH + sA1) = rah1; *(h8_t*)(AsL + sA1) = ral1;
    if (srow < 64){ *(h8_t*)(BsH + sA0) = rbh0; *(h8_t*)(BsL + sA0) = rbl0; }
    else          { *(h8_t*)(BsH + sA1 - 2048) = rbh0; *(h8_t*)(BsL + sA1 - 2048) = rbl0; }
    if (k0 + 32 < K){
      const int kn = k0 + 32;
      rah0 = *(const h8_t*)(pAh + kn);
      rah1 = *(const h8_t*)(pAh + (size_t)64*lda + kn);
      ral0 = *(const h8_t*)(pAl + kn);
      ral1 = *(const h8_t*)(pAl + (size_t)64*lda + kn);
      rb0 = *(const float4*)(pB + kn);
      rb1 = *(const float4*)(pB + kn + 4);
    }
    __syncthreads();
    h8_t ah[4], al[4], bh[2], bl[2];
    #pragma unroll
    for (int m=0;m<4;m++){
      int o = swz(wm + fr + m*16, kg);
      ah[m] = *(const h8_t*)(AsH + o);
      al[m] = *(const h8_t*)(AsL + o);
    }
    #pragma unroll
    for (int n=0;n<2;n++){
      int o = swz(wn + fr + n*16, kg);
      bh[n] = *(const h8_t*)(BsH + o);
      bl[n] = *(const h8_t*)(BsL + o);
    }
    __builtin_amdgcn_s_setprio(1);
    #pragma unroll
    for (int m=0;m<4;m++)
      #pragma unroll
      for (int n=0;n<2;n++){
        acc[m][n] = __builtin_amdgcn_mfma_f32_16x16x32_f16(al[m], bh[n], acc[m][n], 0,0,0);
        acc[m][n] = __builtin_amdgcn_mfma_f32_16x16x32_f16(ah[m], bl[n], acc[m][n], 0,0,0);
        acc[m][n] = __builtin_amdgcn_mfma_f32_16x16x32_f16(ah[m], bh[n], acc[m][n], 0,0,0);
      }
    __builtin_amdgcn_s_setprio(0);
  }
  float bj[2], gj[2];
  #pragma unroll
  for (int n=0;n<2;n++){
    int col = n0 + wn + n*16 + fr;
    bj[n] = bias ? bias[col] : 0.0f;
    gj[n] = gamma[col];
  }
  #pragma unroll
  for (int m=0;m<4;m++){
    #pragma unroll
    for (int r=0;r<4;r++){
      const int row = m0 + wm + m*16 + kg*4 + r;
      #pragma unroll
      for (int n=0;n<2;n++){
        const int col = n0 + wn + n*16 + fr;
        C[(size_t)row*ldc + col] += gj[n]*(acc[m][n][r] + bj[n]);
      }
    }
  }
}

// ---------------- gemm_t (r7-proven core): 512 thr, BM=256 x BN=128; fp32 B split on the fly ---
// Ch/Cl = split(gelu(acc + bias))
__global__ __launch_bounds__(512,2) void gemm_t(
    const _Float16* __restrict__ Ah, const _Float16* __restrict__ Al, int lda,
    const float* __restrict__ W, int ldb,
    const float* __restrict__ bias,
    _Float16* __restrict__ Ch, _Float16* __restrict__ Cl,
    int ldc, int K)
{
  __shared__ _Float16 AsH[8192], AsL[8192], BsH[4096], BsL[4096];
  const int tid = threadIdx.x;
  int bx = blockIdx.x, by = blockIdx.y;
  xcd_remap(bx, by);
  const int m0 = by*256, n0 = bx*128;
  const int srow = tid>>2, kgs = tid&3, koff = kgs*8;   // srow in [0,128)
  const _Float16* pAh = Ah + (size_t)(m0+srow)*lda + koff;
  const _Float16* pAl = Al + (size_t)(m0+srow)*lda + koff;
  const float*    pB  = W  + (size_t)(n0+srow)*ldb + koff;
  const int sA0 = swz(srow, kgs), sA1 = swz(srow+128, kgs);
  const int lane = tid & 63, wid = tid >> 6;
  const int wm = (wid>>1)*64, wn = (wid&1)*64;
  const int fr = lane & 15, kg = lane >> 4;
  f4_t acc[4][4] = {};
  h8_t rah0 = *(const h8_t*)(pAh);
  h8_t rah1 = *(const h8_t*)(pAh + (size_t)128*lda);
  h8_t ral0 = *(const h8_t*)(pAl);
  h8_t ral1 = *(const h8_t*)(pAl + (size_t)128*lda);
  float4 rb0 = *(const float4*)(pB);
  float4 rb1 = *(const float4*)(pB + 4);
  for (int k0 = 0; k0 < K; k0 += 32){
    h8_t rbh0, rbl0;
    split8(rb0, rb1, rbh0, rbl0);
    __syncthreads();
    *(h8_t*)(AsH + sA0) = rah0; *(h8_t*)(AsL + sA0) = ral0;
    *(h8_t*)(AsH + sA1) = rah1; *(h8_t*)(AsL + sA1) = ral1;
    *(h8_t*)(BsH + sA0) = rbh0; *(h8_t*)(BsL + sA0) = rbl0;
    if (k0 + 32 < K){
      const int kn = k0 + 32;
      rah0 = *(const h8_t*)(pAh + kn);
      rah1 = *(const h8_t*)(pAh + (size_t)128*lda + kn);
      ral0 = *(const h8_t*)(pAl + kn);
      ral1 = *(const h8_t*)(pAl + (size_t)128*lda + kn);
      rb0 = *(const float4*)(pB + kn);
      rb1 = *(const float4*)(pB + kn + 4);
    }
    __syncthreads();
    h8_t ah[4], al[4], bh[4], bl[4];
    #pragma unroll
    for (int m=0;m<4;m++){
      int o = swz(wm + fr + m*16, kg);
      ah[m] = *(const h8_t*)(AsH + o);
      al[m] = *(const h8_t*)(AsL + o);
    }
    #pragma unroll
    for (int n=0;n<4;n++){
      int o = swz(wn + fr + n*16, kg);
      bh[n] = *(const h8_t*)(BsH + o);
      bl[n] = *(const h8_t*)(BsL + o);
    }
    #pragma unroll
    for (int m=0;m<4;m++)
      #pragma unroll
      for (int n=0;n<4;n++){
        acc[m][n] = __builtin_amdgcn_mfma_f32_16x16x32_f16(al[m], bh[n], acc[m][n], 0,0,0);
        acc[m][n] = __builtin_amdgcn_mfma_f32_16x16x32_f16(ah[m], bl[n], acc[m][n], 0,0,0);
        acc[m][n] = __builtin_amdgcn_mfma_f32_16x16x32_f16(ah[m], bh[n], acc[m][n], 0,0,0);
      }
  }
  float bj[4];
  #pragma unroll
  for (int n=0;n<4;n++){
    int col = n0 + wn + n*16 + fr;
    bj[n] = bias ? bias[col] : 0.0f;
  }
  #pragma unroll
  for (int m=0;m<4;m++){
    #pragma unroll
    for (int r=0;r<4;r++){
      const int row = m0 + wm + m*16 + kg*4 + r;
      #pragma unroll
      for (int n=0;n<4;n++){
        const int col = n0 + wn + n*16 + fr;
        float v = gelu_exact(acc[m][n][r] + bj[n]);
        _Float16 hh = (_Float16)v;
        Ch[(size_t)row*ldc + col] = hh;
        Cl[(size_t)row*ldc + col] = (_Float16)(v - (float)hh);
      }
    }
  }
}

// ---------------- embed conv (r7-proven): 7 shifted NT-GEMMs, pre-split x, BK=32 ----
__global__ __launch_bounds__(256,2) void embed_f16(
    const _Float16* __restrict__ xh, const _Float16* __restrict__ xl,
    const _Float16* __restrict__ wkh, const _Float16* __restrict__ wkl,
    const float* __restrict__ bias, float* __restrict__ C)
{
  __shared__ _Float16 AsH[4096], AsL[4096], BsH[2048], BsL[2048];
  const int tid = threadIdx.x;
  int bx = blockIdx.x, by = blockIdx.y;
  xcd_remap(bx, by);
  const int m0 = by*128, n0 = bx*64;
  const int srow = tid>>2, kgs = tid&3, koff = kgs*8;
  const int sA0 = swz(srow, kgs), sA1 = swz(srow+64, kgs);
  const int lane = tid & 63, wid = tid >> 6;
  const int wm = (wid>>1)*64, wn = (wid&1)*32;
  const int fr = lane & 15, kg = lane >> 4;
  const int r0 = m0 + srow, r1 = r0 + 64;
  const int t0 = r0 & 2047, t1 = r1 & 2047;
  f4_t acc[4][2] = {};
  const h8_t zero8 = {0,0,0,0,0,0,0,0};
  h8_t rah0, rah1, ral0, ral1, rbh0, rbl0;
  auto load_tile = [&](int kt){
    const int k = kt >> 5;
    const int k0 = (kt & 31) << 5;
    const bool v0 = (unsigned)(t0 + k - 3) < 2048u;
    const bool v1 = (unsigned)(t1 + k - 3) < 2048u;
    rah0 = zero8; rah1 = zero8; ral0 = zero8; ral1 = zero8;
    if (v0){
      const size_t o = (size_t)(r0 + k - 3)*1024 + k0 + koff;
      rah0 = *(const h8_t*)(xh + o); ral0 = *(const h8_t*)(xl + o);
    }
    if (v1){
      const size_t o = (size_t)(r1 + k - 3)*1024 + k0 + koff;
      rah1 = *(const h8_t*)(xh + o); ral1 = *(const h8_t*)(xl + o);
    }
    const size_t wo = (size_t)k*393216 + (size_t)(n0+srow)*1024 + k0 + koff;
    rbh0 = *(const h8_t*)(wkh + wo); rbl0 = *(const h8_t*)(wkl + wo);
  };
  load_tile(0);
  for (int kt = 0; kt < 224; ++kt){
    __syncthreads();
    *(h8_t*)(AsH+sA0) = rah0; *(h8_t*)(AsL+sA0) = ral0;
    *(h8_t*)(AsH+sA1) = rah1; *(h8_t*)(AsL+sA1) = ral1;
    *(h8_t*)(BsH+sA0) = rbh0; *(h8_t*)(BsL+sA0) = rbl0;
    if (kt + 1 < 224)
      load_tile(kt+1);
    __syncthreads();
    h8_t ah[4], al[4], bh[2], bl[2];
    #pragma unroll
    for (int m=0;m<4;m++){
      int o = swz(wm + fr + m*16, kg);
      ah[m] = *(const h8_t*)(AsH + o);
      al[m] = *(const h8_t*)(AsL + o);
    }
    #pragma unroll
    for (int n=0;n<2;n++){
      int o = swz(wn + fr + n*16, kg);
      bh[n] = *(const h8_t*)(BsH + o);
      bl[n] = *(const h8_t*)(BsL + o);
    }
    #pragma unroll
    for (int m=0;m<4;m++)
      #pragma unroll
      for (int n=0;n<2;n++){
        acc[m][n] = __builtin_amdgcn_mfma_f32_16x16x32_f16(al[m], bh[n], acc[m][n], 0,0,0);
        acc[m][n] = __builtin_amdgcn_mfma_f32_16x16x32_f16(ah[m], bl[n], acc[m][n], 0,0,0);
        acc[m][n] = __builtin_amdgcn_mfma_f32_16x16x32_f16(ah[m], bh[n], acc[m][n], 0,0,0);
      }
  }
  #pragma unroll
  for (int m=0;m<4;m++){
    #pragma unroll
    for (int r=0;r<4;r++){
      const int row = m0 + wm + m*16 + kg*4 + r;
      #pragma unroll
      for (int n=0;n<2;n++){
        const int col = n0 + wn + n*16 + fr;
        C[(size_t)row*384 + col] = acc[m][n][r] + bias[col];
      }
    }
  }
}

// ---------------- LN: wave-per-row, barrier-free (r12-proven) ----------------
template<bool CONV, bool SPLIT>
__global__ __launch_bounds__(256) void ln_wave(
    const float* __restrict__ in,
    const float* __restrict__ dw, const float* __restrict__ db,
    const float* __restrict__ g, const float* __restrict__ b,
    float* __restrict__ out, _Float16* __restrict__ oh, _Float16* __restrict__ ol)
{
  const int tid = threadIdx.x;
  const int lane = tid & 63, wid = tid >> 6;
  const int m = blockIdx.x*4 + wid;
  float v[6];
  if (CONV){
    const int t = m & 2047;
    #pragma unroll
    for (int j=0;j<6;j++){
      const int d = j*64 + lane;
      float a = db[d];
      #pragma unroll
      for (int k=0;k<7;k++){
        int tt = t + k - 3;
        if ((unsigned)tt < 2048u) a = fmaf(in[(size_t)(m + k - 3)*384 + d], dw[d*7 + k], a);
      }
      v[j] = a;
    }
  } else {
    #pragma unroll
    for (int j=0;j<6;j++) v[j] = in[(size_t)m*384 + j*64 + lane];
  }
  float s = 0.f, s2 = 0.f;
  #pragma unroll
  for (int j=0;j<6;j++){ s += v[j]; s2 += v[j]*v[j]; }
  #pragma unroll
  for (int o=1;o<64;o<<=1){ s += __shfl_xor(s,o); s2 += __shfl_xor(s2,o); }
  const float mean = s*(1.0f/384.0f);
  const float var = fmaxf(s2*(1.0f/384.0f) - mean*mean, 0.0f);
  const float rstd = 1.0f/sqrtf(var + 1e-6f);
  #pragma unroll
  for (int j=0;j<6;j++){
    const int d = j*64 + lane;
    float o = (v[j] - mean)*rstd*g[d] + b[d];
    if (SPLIT){
      _Float16 hh = (_Float16)o;
      oh[(size_t)m*384 + d] = hh;
      ol[(size_t)m*384 + d] = (_Float16)(o - (float)hh);
    } else {
      out[(size_t)m*384 + d] = o;
    }
  }
}

// ---------------- fused final-LN + z_e projection + normalize ----------------
// wave per token: LN(h) in regs -> dot with cw (LDS) -> zn.
__global__ __launch_bounds__(256) void ln_vq(
    const float* __restrict__ in, const float* __restrict__ g, const float* __restrict__ b,
    const float* __restrict__ cw, const float* __restrict__ cbias, float* __restrict__ zn)
{
  __shared__ float scw[3072];
  const int tid = threadIdx.x;
  for (int i = tid; i < 3072; i += 256) scw[i] = cw[i];
  __syncthreads();
  const int lane = tid & 63, wid = tid >> 6;
  const int m = blockIdx.x*4 + wid;
  float v[6];
  #pragma unroll
  for (int j=0;j<6;j++) v[j] = in[(size_t)m*384 + j*64 + lane];
  float s = 0.f, s2 = 0.f;
  #pragma unroll
  for (int j=0;j<6;j++){ s += v[j]; s2 += v[j]*v[j]; }
  #pragma unroll
  for (int o=1;o<64;o<<=1){ s += __shfl_xor(s,o); s2 += __shfl_xor(s2,o); }
  const float mean = s*(1.0f/384.0f);
  const float var = fmaxf(s2*(1.0f/384.0f) - mean*mean, 0.0f);
  const float rstd = 1.0f/sqrtf(var + 1e-6f);
  float acc[8] = {};
  #pragma unroll
  for (int j=0;j<6;j++){
    const int d = j*64 + lane;
    const float y = (v[j] - mean)*rstd*g[d] + b[d];
    #pragma unroll
    for (int cd=0;cd<8;cd++) acc[cd] = fmaf(y, scw[cd*384 + d], acc[cd]);
  }
  #pragma unroll
  for (int cd=0;cd<8;cd++)
    #pragma unroll
    for (int o=1;o<64;o<<=1) acc[cd] += __shfl_xor(acc[cd], o);
  if (lane == 0){
    float z[8], ss = 0.f;
    #pragma unroll
    for (int cd=0;cd<8;cd++){ z[cd] = acc[cd] + cbias[cd]; ss += z[cd]*z[cd]; }
    float inv = 1.0f / fmaxf(sqrtf(ss), 1e-12f);
    #pragma unroll
    for (int cd=0;cd<8;cd++) zn[(size_t)m*8+cd] = z[cd]*inv;
  }
}

// ---------------- VQ argmax + out ----------------

__global__ __launch_bounds__(256) void vq_argmax(
    const float* __restrict__ zn, const float* __restrict__ cbn,
    int* __restrict__ idx_out, float* __restrict__ idx_f)
{
  __shared__ float sbest[256];
  __shared__ int   sidx[256];
  const int tid = threadIdx.x;
  const int tok = tid & 31, ch = tid >> 5;
  const size_t m = (size_t)blockIdx.x*32 + tok;
  float4 z0 = *(const float4*)&zn[m*8];
  float4 z1 = *(const float4*)&zn[m*8+4];
  float best = -1e30f; int bidx = 0;
  const float* cp = cbn + (size_t)ch*8192;
  #pragma unroll 4
  for (int e = 0; e < 1024; ++e){
    const float4 ca  = *(const float4*)&cp[e*8];
    const float4 cb4 = *(const float4*)&cp[e*8+4];
    float s = z0.x*ca.x + z0.y*ca.y + z0.z*ca.z + z0.w*ca.w
            + z1.x*cb4.x + z1.y*cb4.y + z1.z*cb4.z + z1.w*cb4.w;
    if (s > best){ best = s; bidx = ch*1024 + e; }
  }
  sbest[tid] = best; sidx[tid] = bidx;
  __syncthreads();
  if (tid < 32){
    float b = sbest[tid]; int bi = sidx[tid];
    #pragma unroll
    for (int c=1;c<8;c++){
      float ob = sbest[c*32 + tid];
      if (ob > b){ b = ob; bi = sidx[c*32 + tid]; }
    }
    idx_out[(size_t)blockIdx.x*32 + tid] = bi;
    idx_f [(size_t)blockIdx.x*32 + tid] = (float)bi;
  }
}

__global__ __launch_bounds__(256) void vq_out_kernel(
    const int* __restrict__ idx, const float* __restrict__ cb,
    const float* __restrict__ wo, const float* __restrict__ bo,
    float* __restrict__ outq)
{
  __shared__ float wT[8][1024];
  __shared__ float cbs[16][8];
  __shared__ int idxs[16];
  const int tid = threadIdx.x;
  #pragma unroll
  for (int j=0;j<4;j++){
    int hcol = j*256 + tid;
    float4 w0 = *(const float4*)&wo[(size_t)hcol*8];
    float4 w1 = *(const float4*)&wo[(size_t)hcol*8+4];
    wT[0][hcol]=w0.x; wT[1][hcol]=w0.y; wT[2][hcol]=w0.z; wT[3][hcol]=w0.w;
    wT[4][hcol]=w1.x; wT[5][hcol]=w1.y; wT[6][hcol]=w1.z; wT[7][hcol]=w1.w;
  }
  if (tid < 16) idxs[tid] = idx[blockIdx.x*16 + tid];
  __syncthreads();
  if (tid < 128){ int tk = tid>>3, cd = tid&7; cbs[tk][cd] = cb[(size_t)idxs[tk]*8 + cd]; }
  __syncthreads();
  float bb[4];
  #pragma unroll
  for (int j=0;j<4;j++) bb[j] = bo[j*256+tid];
  for (int tk=0;tk<16;tk++){
    const size_t m = (size_t)blockIdx.x*16 + tk;
    float c0=cbs[tk][0], c1=cbs[tk][1], c2=cbs[tk][2], c3=cbs[tk][3];
    float c4=cbs[tk][4], c5=cbs[tk][5], c6=cbs[tk][6], c7=cbs[tk][7];
    #pragma unroll
    for (int j=0;j<4;j++){
      int hcol = j*256 + tid;
      float v = bb[j];
      v = fmaf(c0, wT[0][hcol], v); v = fmaf(c1, wT[1][hcol], v);
      v = fmaf(c2, wT[2][hcol], v); v = fmaf(c3, wT[3][hcol], v);
      v = fmaf(c4, wT[4][hcol], v); v = fmaf(c5, wT[5][hcol], v);
      v = fmaf(c6, wT[6][hcol], v); v = fmaf(c7, wT[7][hcol], v);
      outq[m*1024 + hcol] = v;
    }
  }
}

// ---------------- host ----------------

extern "C" void kernel_launch(void* const* d_in, const int* in_sizes, int n_in,
                              void* d_out, int out_size, void* d_ws, size_t ws_size,
                              hipStream_t stream) {
  (void)in_sizes; (void)n_in; (void)out_size; (void)ws_size;
  const float* x   = (const float*)d_in[0];
  const float* eww = (const float*)d_in[1];
  const float* ewb = (const float*)d_in[2];
  const float* ng  = (const float*)d_in[3];
  const float* nb  = (const float*)d_in[4];
  const float* dww = (const float*)d_in[5];
  const float* dwb = (const float*)d_in[6];
  const float* lng = (const float*)d_in[7];
  const float* lnb = (const float*)d_in[8];
  const float* w1  = (const float*)d_in[9];
  const float* b1  = (const float*)d_in[10];
  const float* w2  = (const float*)d_in[11];
  const float* b2  = (const float*)d_in[12];
  const float* gma = (const float*)d_in[13];
  const float* fg  = (const float*)d_in[14];
  const float* fb  = (const float*)d_in[15];
  const float* ow  = (const float*)d_in[16];
  const float* ob  = (const float*)d_in[17];
  const float* viw = (const float*)d_in[18];
  const float* vib = (const float*)d_in[19];
  const float* cb  = (const float*)d_in[20];
  const float* vow = (const float*)d_in[21];
  const float* vob = (const float*)d_in[22];
  float* out = (float*)d_out;

  // workspace layout (f32 units), 32,112,640 f = 122.5 MiB (superset of r13 base):
  // wreg [0, 2752512): wk halves (embed); tail (post-blocks): zn/cbn/idx/cw/cbias
  // h    [2752512, 9043968): residual fp32
  // yl   [9043968, 15335424): embed-out fp32 -> LN-out splits
  // y1   [15335424, 32112640): x splits (embed) -> y1 splits (blocks)
  float* ws = (float*)d_ws;
  float* wreg = ws;
  _Float16* wkh = (_Float16*)wreg;
  _Float16* wkl = wkh + 2752512;
  float* zn  = wreg + 1048576;
  float* cbn = wreg + 1179648;
  int*  idxb = (int*)(wreg + 1245184);
  float* cw  = wreg + 1261568;
  float* cbias = wreg + 1264640;
  float* h   = ws + 2752512;
  float* ylreg = ws + 9043968;
  float* yf32 = ylreg;
  _Float16* ylh = (_Float16*)ylreg;
  _Float16* yll = ylh + 6291456;
  float* y1reg = ws + 15335424;
  _Float16* xh  = (_Float16*)y1reg;
  _Float16* xl  = xh + 16777216;
  _Float16* y1h = (_Float16*)y1reg;
  _Float16* y1l = y1h + 16777216;

  // prep: wk splits + x splits; embed -> yf32; LN -> h
  prep_wk_split<<<dim3(1536), dim3(256), 0, stream>>>(eww, wkh, wkl);
  split_one<<<dim3(16384), dim3(256), 0, stream>>>(x, xh, xl, 4194304);
  embed_f16<<<dim3(6,128), dim3(256), 0, stream>>>(xh, xl, wkh, wkl, ewb, yf32);
  ln_wave<false,false><<<dim3(4096), dim3(256), 0, stream>>>(
      yf32, nullptr, nullptr, ng, nb, h, nullptr, nullptr);

  // 12 ConvNeXt blocks (weights split on the fly inside GEMM staging)
  for (int i = 0; i < 12; ++i){
    ln_wave<true,true><<<dim3(4096), dim3(256), 0, stream>>>(
        h, dww + (size_t)i*2688, dwb + (size_t)i*384,
        lng + (size_t)i*384, lnb + (size_t)i*384, nullptr, ylh, yll);
    for (int ic = 0; ic < 2; ++ic){
      // y1 = gelu(y @ w1_chunk^T + b1_chunk): M=16384, N=1024, K=384
      gemm_t<<<dim3(8,64), dim3(512), 0, stream>>>(
          ylh, yll, 384,
          w1 + (size_t)i*786432 + (size_t)ic*393216, 384,
          b1 + (size_t)i*2048 + (size_t)ic*1024,
          y1h, y1l, 1024, 384);
      // h += gamma * (y1 @ w2_chunk^T + b2(once)): M=16384, N=384, K=1024
      gemm_n64<<<dim3(6,128), dim3(256), 0, stream>>>(
          y1h, y1l, 1024,
          w2 + (size_t)i*786432 + (size_t)ic*1024, 2048,
          (ic == 0) ? (b2 + (size_t)i*384) : nullptr,
          gma + (size_t)i*384,
          h, 384, 1024);
    }
  }

  // VQ: prep (cw fold + cbn), fused final-LN + z_e, argmax, out-proj
  prep_vq<<<dim3(44), dim3(256), 0, stream>>>(viw, ow, vib, ob, cb, cw, cbias, cbn);
  ln_vq<<<dim3(4096), dim3(256), 0, stream>>>(h, fg, fb, cw, cbias, zn);
  vq_argmax<<<dim3(512), dim3(256), 0, stream>>>(zn, cbn, idxb, out);
  vq_out_kernel<<<dim3(1024), dim3(256), 0, stream>>>(idxb, cb, vow, vob, out + 16384);
}

// Round 15
// 3497.893 us; speedup vs baseline: 1.0208x; 1.0208x over previous
//
#include <hip/hip_runtime.h>
#include <math.h>

// RepCodec: Vocos encoder + factorized VQ.
// GEMMs on MFMA via fp16 two-term split (hi+lo), 3 passes: hh + hl + lh.
// Round 15: r13 (best measured: pre-split weights, frozen GEMM core) +
// r14's fused final-LN+vq_ze (deletes 48MB of yf32 traffic + 1 launch).

typedef _Float16 h8_t __attribute__((ext_vector_type(8)));
typedef _Float16 h4_t __attribute__((ext_vector_type(4)));
typedef float f4_t __attribute__((ext_vector_type(4)));

__device__ __forceinline__ float gelu_exact(float x){
  return 0.5f * x * (1.0f + erff(x * 0.70710678118654752f));
}

__device__ __forceinline__ void split4(const float4& a, h4_t& hi, h4_t& lo){
  float f[4] = {a.x,a.y,a.z,a.w};
  #pragma unroll
  for (int t=0;t<4;t++){
    _Float16 hh = (_Float16)f[t];
    hi[t] = hh;
    lo[t] = (_Float16)(f[t] - (float)hh);
  }
}

// LDS slot swizzle (r3/r6-measured: SQ_LDS_BANK_CONFLICT == 0 with tid>>2 staging).
__device__ __forceinline__ int swz(int row, int kg){
  return row*32 + ((kg ^ ((row>>1)&3))<<3);
}

// XCD-aware bijective block swizzle (grids with nwg%8==0)
__device__ __forceinline__ void xcd_remap(int& bx, int& by){
  const int gx = gridDim.x;
  const int nwg = gx * gridDim.y;
  int bid = by*gx + bx;
  if ((nwg & 7) == 0){
    bid = (bid & 7)*(nwg >> 3) + (bid >> 3);
    bx = bid % gx; by = bid / gx;
  }
}

// ---------------- prep kernels ----------------

__global__ __launch_bounds__(256) void prep_wk_split(const float* __restrict__ w,
                                                     _Float16* __restrict__ wh,
                                                     _Float16* __restrict__ wl){
  int i = blockIdx.x*256 + threadIdx.x;
  if (i >= 384*1024) return;
  int d = i >> 10, c = i & 1023;
  #pragma unroll
  for (int k=0;k<7;k++){
    float v = w[(size_t)d*(1024*7) + (size_t)c*7 + k];
    _Float16 hh = (_Float16)v;
    wh[(size_t)k*393216 + i] = hh;
    wl[(size_t)k*393216 + i] = (_Float16)(v - (float)hh);
  }
}

// Merged VQ prep: blocks 0-11 -> cw fold (+cbias on block 0); blocks 12-43 -> cbn.
__global__ __launch_bounds__(256) void prep_vq(const float* __restrict__ viw, const float* __restrict__ ow,
                                               const float* __restrict__ vib, const float* __restrict__ ob,
                                               const float* __restrict__ cb,
                                               float* __restrict__ cw, float* __restrict__ cbias,
                                               float* __restrict__ cbn){
  const int blk = blockIdx.x, tid = threadIdx.x;
  if (blk < 12){
    int i = blk*256 + tid;
    if (i < 3072){
      int c = i / 384, d = i - c*384;
      float acc = 0.f;
      for (int h=0; h<1024; ++h)
        acc = fmaf(viw[c*1024+h], ow[(size_t)h*384 + d], acc);
      cw[i] = acc;
    }
    if (blk == 0 && tid < 8){
      int c = tid;
      float acc = vib[c];
      for (int h=0; h<1024; ++h) acc = fmaf(viw[c*1024+h], ob[h], acc);
      cbias[c] = acc;
    }
  } else {
    int e = (blk-12)*256 + tid;
    float v[8], s = 0.f;
    #pragma unroll
    for (int cd=0; cd<8; ++cd){ v[cd] = cb[(size_t)e*8+cd]; s += v[cd]*v[cd]; }
    float inv = 1.0f / fmaxf(sqrtf(s), 1e-12f);
    #pragma unroll
    for (int cd=0; cd<8; ++cd) cbn[(size_t)e*8+cd] = v[cd]*inv;
  }
}

__global__ __launch_bounds__(256) void split_pair(const float* __restrict__ a, const float* __restrict__ b,
                                                  _Float16* __restrict__ ah, _Float16* __restrict__ al,
                                                  _Float16* __restrict__ bh, _Float16* __restrict__ bl,
                                                  int n4){
  int i = blockIdx.x*256 + threadIdx.x;
  if (i >= n4) return;
  h4_t hi, lo;
  float4 va = ((const float4*)a)[i];
  split4(va, hi, lo);
  ((h4_t*)ah)[i] = hi; ((h4_t*)al)[i] = lo;
  float4 vb = ((const float4*)b)[i];
  split4(vb, hi, lo);
  ((h4_t*)bh)[i] = hi; ((h4_t*)bl)[i] = lo;
}

// One-shot split of all 12 layers' w1/w2 (grid 768 x 12).
__global__ __launch_bounds__(256) void split_pair_all(
    const float* __restrict__ a, const float* __restrict__ b,
    _Float16* __restrict__ ah, _Float16* __restrict__ al,
    _Float16* __restrict__ bh, _Float16* __restrict__ bl){
  const int L = blockIdx.y;
  const int i = blockIdx.x*256 + threadIdx.x;          // < 196608 float4s
  const size_t fo = (size_t)L*786432;
  h4_t hi, lo;
  float4 va = ((const float4*)(a + fo))[i];
  split4(va, hi, lo);
  ((h4_t*)(ah + fo))[i] = hi; ((h4_t*)(al + fo))[i] = lo;
  float4 vb = ((const float4*)(b + fo))[i];
  split4(vb, hi, lo);
  ((h4_t*)(bh + fo))[i] = hi; ((h4_t*)(bl + fo))[i] = lo;
}

__global__ __launch_bounds__(256) void split_one(const float* __restrict__ a,
                                                 _Float16* __restrict__ ah, _Float16* __restrict__ al,
                                                 int n4){
  int i = blockIdx.x*256 + threadIdx.x;
  if (i >= n4) return;
  h4_t hi, lo;
  float4 va = ((const float4*)a)[i];
  split4(va, hi, lo);
  ((h4_t*)ah)[i] = hi; ((h4_t*)al)[i] = lo;
}

// ---------------- gemm_s (r6-proven): 256 thr, BM=128, BN=64, BK=32 ----------------
// EPI 2: C(fp32) += gamma * (acc + bias?)
template<int BN, int EPI>
__global__ __launch_bounds__(256,2) void gemm_s(
    const _Float16* __restrict__ Ah, const _Float16* __restrict__ Al, int lda,
    const _Float16* __restrict__ Bh, const _Float16* __restrict__ Bl, int ldb,
    const float* __restrict__ bias, const float* __restrict__ gamma,
    float* __restrict__ C, _Float16* __restrict__ Ch, _Float16* __restrict__ Cl,
    int ldc, int K)
{
  constexpr int NF = BN/32;
  __shared__ _Float16 AsH[4096], AsL[4096];
  __shared__ _Float16 BsH[BN*32], BsL[BN*32];
  const int tid = threadIdx.x;
  int bx = blockIdx.x, by = blockIdx.y;
  xcd_remap(bx, by);
  const int m0 = by*128, n0 = bx*BN;
  const int srow = tid>>2, kgs = tid&3, koff = kgs*8;
  const _Float16* pAh = Ah + (size_t)(m0+srow)*lda + koff;
  const _Float16* pAl = Al + (size_t)(m0+srow)*lda + koff;
  const _Float16* pBh = Bh + (size_t)(n0+srow)*ldb + koff;
  const _Float16* pBl = Bl + (size_t)(n0+srow)*ldb + koff;
  const int sA0 = swz(srow, kgs), sA1 = swz(srow+64, kgs);
  const int lane = tid & 63, wid = tid >> 6;
  const int wm = (wid>>1)*64, wn = (wid&1)*(BN/2);
  const int fr = lane & 15, kg = lane >> 4;
  f4_t acc[4][NF] = {};
  h8_t rah0 = *(const h8_t*)(pAh);
  h8_t rah1 = *(const h8_t*)(pAh + (size_t)64*lda);
  h8_t ral0 = *(const h8_t*)(pAl);
  h8_t ral1 = *(const h8_t*)(pAl + (size_t)64*lda);
  h8_t rbh0 = *(const h8_t*)(pBh);
  h8_t rbl0 = *(const h8_t*)(pBl);
  h8_t rbh1, rbl1;
  if constexpr (BN == 128){
    rbh1 = *(const h8_t*)(pBh + (size_t)64*ldb);
    rbl1 = *(const h8_t*)(pBl + (size_t)64*ldb);
  }
  for (int k0 = 0; k0 < K; k0 += 32){
    __syncthreads();
    *(h8_t*)(AsH + sA0) = rah0; *(h8_t*)(AsL + sA0) = ral0;
    *(h8_t*)(AsH + sA1) = rah1; *(h8_t*)(AsL + sA1) = ral1;
    if constexpr (BN == 128){
      *(h8_t*)(BsH + sA0) = rbh0; *(h8_t*)(BsL + sA0) = rbl0;
      *(h8_t*)(BsH + sA1) = rbh1; *(h8_t*)(BsL + sA1) = rbl1;
    } else {
      if (srow < 64){ *(h8_t*)(BsH + sA0) = rbh0; *(h8_t*)(BsL + sA0) = rbl0; }
      else          { *(h8_t*)(BsH + sA1 - 2048) = rbh0; *(h8_t*)(BsL + sA1 - 2048) = rbl0; }
    }
    if (k0 + 32 < K){
      const int kn = k0 + 32;
      rah0 = *(const h8_t*)(pAh + kn);
      rah1 = *(const h8_t*)(pAh + (size_t)64*lda + kn);
      ral0 = *(const h8_t*)(pAl + kn);
      ral1 = *(const h8_t*)(pAl + (size_t)64*lda + kn);
      rbh0 = *(const h8_t*)(pBh + kn);
      rbl0 = *(const h8_t*)(pBl + kn);
      if constexpr (BN == 128){
        rbh1 = *(const h8_t*)(pBh + (size_t)64*ldb + kn);
        rbl1 = *(const h8_t*)(pBl + (size_t)64*ldb + kn);
      }
    }
    __syncthreads();
    h8_t ah[4], al[4], bh[NF], bl[NF];
    #pragma unroll
    for (int m=0;m<4;m++){
      int o = swz(wm + fr + m*16, kg);
      ah[m] = *(const h8_t*)(AsH + o);
      al[m] = *(const h8_t*)(AsL + o);
    }
    #pragma unroll
    for (int n=0;n<NF;n++){
      int o = swz(wn + fr + n*16, kg);
      bh[n] = *(const h8_t*)(BsH + o);
      bl[n] = *(const h8_t*)(BsL + o);
    }
    __builtin_amdgcn_s_setprio(1);
    #pragma unroll
    for (int m=0;m<4;m++)
      #pragma unroll
      for (int n=0;n<NF;n++){
        acc[m][n] = __builtin_amdgcn_mfma_f32_16x16x32_f16(al[m], bh[n], acc[m][n], 0,0,0);
        acc[m][n] = __builtin_amdgcn_mfma_f32_16x16x32_f16(ah[m], bl[n], acc[m][n], 0,0,0);
        acc[m][n] = __builtin_amdgcn_mfma_f32_16x16x32_f16(ah[m], bh[n], acc[m][n], 0,0,0);
      }
    __builtin_amdgcn_s_setprio(0);
  }
  float bj[NF], gj[NF];
  #pragma unroll
  for (int n=0;n<NF;n++){
    int col = n0 + wn + n*16 + fr;
    bj[n] = bias ? bias[col] : 0.0f;
    gj[n] = (EPI==2) ? gamma[col] : 0.0f;
  }
  #pragma unroll
  for (int m=0;m<4;m++){
    #pragma unroll
    for (int r=0;r<4;r++){
      const int row = m0 + wm + m*16 + kg*4 + r;
      #pragma unroll
      for (int n=0;n<NF;n++){
        const int col = n0 + wn + n*16 + fr;
        float v = acc[m][n][r] + bj[n];
        if (EPI==0){
          C[(size_t)row*ldc + col] = v;
        } else if (EPI==1){
          v = gelu_exact(v);
          _Float16 hh = (_Float16)v;
          Ch[(size_t)row*ldc + col] = hh;
          Cl[(size_t)row*ldc + col] = (_Float16)(v - (float)hh);
        } else if (EPI==2){
          C[(size_t)row*ldc + col] += gj[n]*v;
        } else {
          _Float16 hh = (_Float16)v;
          Ch[(size_t)row*ldc + col] = hh;
          Cl[(size_t)row*ldc + col] = (_Float16)(v - (float)hh);
        }
      }
    }
  }
}

// ---------------- gemm_t (r7-proven): 512 thr, BM=256 x BN=128, 8 waves (4m x 2n) ----------------
// EPI 1: Ch/Cl=split(gelu(v))
template<int EPI>
__global__ __launch_bounds__(512,2) void gemm_t(
    const _Float16* __restrict__ Ah, const _Float16* __restrict__ Al, int lda,
    const _Float16* __restrict__ Bh, const _Float16* __restrict__ Bl, int ldb,
    const float* __restrict__ bias,
    _Float16* __restrict__ Ch, _Float16* __restrict__ Cl,
    int ldc, int K)
{
  __shared__ _Float16 AsH[8192], AsL[8192], BsH[4096], BsL[4096];
  const int tid = threadIdx.x;
  int bx = blockIdx.x, by = blockIdx.y;
  xcd_remap(bx, by);
  const int m0 = by*256, n0 = bx*128;
  const int srow = tid>>2, kgs = tid&3, koff = kgs*8;   // srow in [0,128)
  const _Float16* pAh = Ah + (size_t)(m0+srow)*lda + koff;
  const _Float16* pAl = Al + (size_t)(m0+srow)*lda + koff;
  const _Float16* pBh = Bh + (size_t)(n0+srow)*ldb + koff;
  const _Float16* pBl = Bl + (size_t)(n0+srow)*ldb + koff;
  const int sA0 = swz(srow, kgs), sA1 = swz(srow+128, kgs);
  const int lane = tid & 63, wid = tid >> 6;
  const int wm = (wid>>1)*64, wn = (wid&1)*64;
  const int fr = lane & 15, kg = lane >> 4;
  f4_t acc[4][4] = {};
  h8_t rah0 = *(const h8_t*)(pAh);
  h8_t rah1 = *(const h8_t*)(pAh + (size_t)128*lda);
  h8_t ral0 = *(const h8_t*)(pAl);
  h8_t ral1 = *(const h8_t*)(pAl + (size_t)128*lda);
  h8_t rbh0 = *(const h8_t*)(pBh);
  h8_t rbl0 = *(const h8_t*)(pBl);
  for (int k0 = 0; k0 < K; k0 += 32){
    __syncthreads();
    *(h8_t*)(AsH + sA0) = rah0; *(h8_t*)(AsL + sA0) = ral0;
    *(h8_t*)(AsH + sA1) = rah1; *(h8_t*)(AsL + sA1) = ral1;
    *(h8_t*)(BsH + sA0) = rbh0; *(h8_t*)(BsL + sA0) = rbl0;
    if (k0 + 32 < K){
      const int kn = k0 + 32;
      rah0 = *(const h8_t*)(pAh + kn);
      rah1 = *(const h8_t*)(pAh + (size_t)128*lda + kn);
      ral0 = *(const h8_t*)(pAl + kn);
      ral1 = *(const h8_t*)(pAl + (size_t)128*lda + kn);
      rbh0 = *(const h8_t*)(pBh + kn);
      rbl0 = *(const h8_t*)(pBl + kn);
    }
    __syncthreads();
    h8_t ah[4], al[4], bh[4], bl[4];
    #pragma unroll
    for (int m=0;m<4;m++){
      int o = swz(wm + fr + m*16, kg);
      ah[m] = *(const h8_t*)(AsH + o);
      al[m] = *(const h8_t*)(AsL + o);
    }
    #pragma unroll
    for (int n=0;n<4;n++){
      int o = swz(wn + fr + n*16, kg);
      bh[n] = *(const h8_t*)(BsH + o);
      bl[n] = *(const h8_t*)(BsL + o);
    }
    #pragma unroll
    for (int m=0;m<4;m++)
      #pragma unroll
      for (int n=0;n<4;n++){
        acc[m][n] = __builtin_amdgcn_mfma_f32_16x16x32_f16(al[m], bh[n], acc[m][n], 0,0,0);
        acc[m][n] = __builtin_amdgcn_mfma_f32_16x16x32_f16(ah[m], bl[n], acc[m][n], 0,0,0);
        acc[m][n] = __builtin_amdgcn_mfma_f32_16x16x32_f16(ah[m], bh[n], acc[m][n], 0,0,0);
      }
  }
  float bj[4];
  #pragma unroll
  for (int n=0;n<4;n++){
    int col = n0 + wn + n*16 + fr;
    bj[n] = bias ? bias[col] : 0.0f;
  }
  #pragma unroll
  for (int m=0;m<4;m++){
    #pragma unroll
    for (int r=0;r<4;r++){
      const int row = m0 + wm + m*16 + kg*4 + r;
      #pragma unroll
      for (int n=0;n<4;n++){
        const int col = n0 + wn + n*16 + fr;
        float v = acc[m][n][r] + bj[n];
        if (EPI==1) v = gelu_exact(v);
        _Float16 hh = (_Float16)v;
        Ch[(size_t)row*ldc + col] = hh;
        Cl[(size_t)row*ldc + col] = (_Float16)(v - (float)hh);
      }
    }
  }
}

// ---------------- embed conv (r7-proven): 7 shifted NT-GEMMs, pre-split x, BK=32 ----
__global__ __launch_bounds__(256,2) void embed_f16(
    const _Float16* __restrict__ xh, const _Float16* __restrict__ xl,
    const _Float16* __restrict__ wkh, const _Float16* __restrict__ wkl,
    const float* __restrict__ bias, float* __restrict__ C)
{
  __shared__ _Float16 AsH[4096], AsL[4096], BsH[2048], BsL[2048];
  const int tid = threadIdx.x;
  int bx = blockIdx.x, by = blockIdx.y;
  xcd_remap(bx, by);
  const int m0 = by*128, n0 = bx*64;
  const int srow = tid>>2, kgs = tid&3, koff = kgs*8;
  const int sA0 = swz(srow, kgs), sA1 = swz(srow+64, kgs);
  const int lane = tid & 63, wid = tid >> 6;
  const int wm = (wid>>1)*64, wn = (wid&1)*32;
  const int fr = lane & 15, kg = lane >> 4;
  const int r0 = m0 + srow, r1 = r0 + 64;
  const int t0 = r0 & 2047, t1 = r1 & 2047;
  f4_t acc[4][2] = {};
  const h8_t zero8 = {0,0,0,0,0,0,0,0};
  h8_t rah0, rah1, ral0, ral1, rbh0, rbl0;
  auto load_tile = [&](int kt){
    const int k = kt >> 5;
    const int k0 = (kt & 31) << 5;
    const bool v0 = (unsigned)(t0 + k - 3) < 2048u;
    const bool v1 = (unsigned)(t1 + k - 3) < 2048u;
    rah0 = zero8; rah1 = zero8; ral0 = zero8; ral1 = zero8;
    if (v0){
      const size_t o = (size_t)(r0 + k - 3)*1024 + k0 + koff;
      rah0 = *(const h8_t*)(xh + o); ral0 = *(const h8_t*)(xl + o);
    }
    if (v1){
      const size_t o = (size_t)(r1 + k - 3)*1024 + k0 + koff;
      rah1 = *(const h8_t*)(xh + o); ral1 = *(const h8_t*)(xl + o);
    }
    const size_t wo = (size_t)k*393216 + (size_t)(n0+srow)*1024 + k0 + koff;
    rbh0 = *(const h8_t*)(wkh + wo); rbl0 = *(const h8_t*)(wkl + wo);
  };
  load_tile(0);
  for (int kt = 0; kt < 224; ++kt){
    __syncthreads();
    *(h8_t*)(AsH+sA0) = rah0; *(h8_t*)(AsL+sA0) = ral0;
    *(h8_t*)(AsH+sA1) = rah1; *(h8_t*)(AsL+sA1) = ral1;
    *(h8_t*)(BsH+sA0) = rbh0; *(h8_t*)(BsL+sA0) = rbl0;
    if (kt + 1 < 224)
      load_tile(kt+1);
    __syncthreads();
    h8_t ah[4], al[4], bh[2], bl[2];
    #pragma unroll
    for (int m=0;m<4;m++){
      int o = swz(wm + fr + m*16, kg);
      ah[m] = *(const h8_t*)(AsH + o);
      al[m] = *(const h8_t*)(AsL + o);
    }
    #pragma unroll
    for (int n=0;n<2;n++){
      int o = swz(wn + fr + n*16, kg);
      bh[n] = *(const h8_t*)(BsH + o);
      bl[n] = *(const h8_t*)(BsL + o);
    }
    #pragma unroll
    for (int m=0;m<4;m++)
      #pragma unroll
      for (int n=0;n<2;n++){
        acc[m][n] = __builtin_amdgcn_mfma_f32_16x16x32_f16(al[m], bh[n], acc[m][n], 0,0,0);
        acc[m][n] = __builtin_amdgcn_mfma_f32_16x16x32_f16(ah[m], bl[n], acc[m][n], 0,0,0);
        acc[m][n] = __builtin_amdgcn_mfma_f32_16x16x32_f16(ah[m], bh[n], acc[m][n], 0,0,0);
      }
  }
  #pragma unroll
  for (int m=0;m<4;m++){
    #pragma unroll
    for (int r=0;r<4;r++){
      const int row = m0 + wm + m*16 + kg*4 + r;
      #pragma unroll
      for (int n=0;n<2;n++){
        const int col = n0 + wn + n*16 + fr;
        C[(size_t)row*384 + col] = acc[m][n][r] + bias[col];
      }
    }
  }
}

// ---------------- LN: wave-per-row, barrier-free (r12-proven) ----------------
template<bool CONV, bool SPLIT>
__global__ __launch_bounds__(256) void ln_wave(
    const float* __restrict__ in,
    const float* __restrict__ dw, const float* __restrict__ db,
    const float* __restrict__ g, const float* __restrict__ b,
    float* __restrict__ out, _Float16* __restrict__ oh, _Float16* __restrict__ ol)
{
  const int tid = threadIdx.x;
  const int lane = tid & 63, wid = tid >> 6;
  const int m = blockIdx.x*4 + wid;
  float v[6];
  if (CONV){
    const int t = m & 2047;
    #pragma unroll
    for (int j=0;j<6;j++){
      const int d = j*64 + lane;
      float a = db[d];
      #pragma unroll
      for (int k=0;k<7;k++){
        int tt = t + k - 3;
        if ((unsigned)tt < 2048u) a = fmaf(in[(size_t)(m + k - 3)*384 + d], dw[d*7 + k], a);
      }
      v[j] = a;
    }
  } else {
    #pragma unroll
    for (int j=0;j<6;j++) v[j] = in[(size_t)m*384 + j*64 + lane];
  }
  float s = 0.f, s2 = 0.f;
  #pragma unroll
  for (int j=0;j<6;j++){ s += v[j]; s2 += v[j]*v[j]; }
  #pragma unroll
  for (int o=1;o<64;o<<=1){ s += __shfl_xor(s,o); s2 += __shfl_xor(s2,o); }
  const float mean = s*(1.0f/384.0f);
  const float var = fmaxf(s2*(1.0f/384.0f) - mean*mean, 0.0f);
  const float rstd = 1.0f/sqrtf(var + 1e-6f);
  #pragma unroll
  for (int j=0;j<6;j++){
    const int d = j*64 + lane;
    float o = (v[j] - mean)*rstd*g[d] + b[d];
    if (SPLIT){
      _Float16 hh = (_Float16)o;
      oh[(size_t)m*384 + d] = hh;
      ol[(size_t)m*384 + d] = (_Float16)(o - (float)hh);
    } else {
      out[(size_t)m*384 + d] = o;
    }
  }
}

// ---------------- fused final-LN + z_e projection + normalize (r14-proven) ----------------
__global__ __launch_bounds__(256) void ln_vq(
    const float* __restrict__ in, const float* __restrict__ g, const float* __restrict__ b,
    const float* __restrict__ cw, const float* __restrict__ cbias, float* __restrict__ zn)
{
  __shared__ float scw[3072];
  const int tid = threadIdx.x;
  for (int i = tid; i < 3072; i += 256) scw[i] = cw[i];
  __syncthreads();
  const int lane = tid & 63, wid = tid >> 6;
  const int m = blockIdx.x*4 + wid;
  float v[6];
  #pragma unroll
  for (int j=0;j<6;j++) v[j] = in[(size_t)m*384 + j*64 + lane];
  float s = 0.f, s2 = 0.f;
  #pragma unroll
  for (int j=0;j<6;j++){ s += v[j]; s2 += v[j]*v[j]; }
  #pragma unroll
  for (int o=1;o<64;o<<=1){ s += __shfl_xor(s,o); s2 += __shfl_xor(s2,o); }
  const float mean = s*(1.0f/384.0f);
  const float var = fmaxf(s2*(1.0f/384.0f) - mean*mean, 0.0f);
  const float rstd = 1.0f/sqrtf(var + 1e-6f);
  float acc[8] = {};
  #pragma unroll
  for (int j=0;j<6;j++){
    const int d = j*64 + lane;
    const float y = (v[j] - mean)*rstd*g[d] + b[d];
    #pragma unroll
    for (int cd=0;cd<8;cd++) acc[cd] = fmaf(y, scw[cd*384 + d], acc[cd]);
  }
  #pragma unroll
  for (int cd=0;cd<8;cd++)
    #pragma unroll
    for (int o=1;o<64;o<<=1) acc[cd] += __shfl_xor(acc[cd], o);
  if (lane == 0){
    float z[8], ss = 0.f;
    #pragma unroll
    for (int cd=0;cd<8;cd++){ z[cd] = acc[cd] + cbias[cd]; ss += z[cd]*z[cd]; }
    float inv = 1.0f / fmaxf(sqrtf(ss), 1e-12f);
    #pragma unroll
    for (int cd=0;cd<8;cd++) zn[(size_t)m*8+cd] = z[cd]*inv;
  }
}

// ---------------- VQ argmax + out ----------------

__global__ __launch_bounds__(256) void vq_argmax(
    const float* __restrict__ zn, const float* __restrict__ cbn,
    int* __restrict__ idx_out, float* __restrict__ idx_f)
{
  __shared__ float sbest[256];
  __shared__ int   sidx[256];
  const int tid = threadIdx.x;
  const int tok = tid & 31, ch = tid >> 5;
  const size_t m = (size_t)blockIdx.x*32 + tok;
  float4 z0 = *(const float4*)&zn[m*8];
  float4 z1 = *(const float4*)&zn[m*8+4];
  float best = -1e30f; int bidx = 0;
  const float* cp = cbn + (size_t)ch*8192;
  #pragma unroll 4
  for (int e = 0; e < 1024; ++e){
    const float4 ca  = *(const float4*)&cp[e*8];
    const float4 cb4 = *(const float4*)&cp[e*8+4];
    float s = z0.x*ca.x + z0.y*ca.y + z0.z*ca.z + z0.w*ca.w
            + z1.x*cb4.x + z1.y*cb4.y + z1.z*cb4.z + z1.w*cb4.w;
    if (s > best){ best = s; bidx = ch*1024 + e; }
  }
  sbest[tid] = best; sidx[tid] = bidx;
  __syncthreads();
  if (tid < 32){
    float b = sbest[tid]; int bi = sidx[tid];
    #pragma unroll
    for (int c=1;c<8;c++){
      float ob = sbest[c*32 + tid];
      if (ob > b){ b = ob; bi = sidx[c*32 + tid]; }
    }
    idx_out[(size_t)blockIdx.x*32 + tid] = bi;
    idx_f [(size_t)blockIdx.x*32 + tid] = (float)bi;
  }
}

__global__ __launch_bounds__(256) void vq_out_kernel(
    const int* __restrict__ idx, const float* __restrict__ cb,
    const float* __restrict__ wo, const float* __restrict__ bo,
    float* __restrict__ outq)
{
  __shared__ float wT[8][1024];
  __shared__ float cbs[16][8];
  __shared__ int idxs[16];
  const int tid = threadIdx.x;
  #pragma unroll
  for (int j=0;j<4;j++){
    int hcol = j*256 + tid;
    float4 w0 = *(const float4*)&wo[(size_t)hcol*8];
    float4 w1 = *(const float4*)&wo[(size_t)hcol*8+4];
    wT[0][hcol]=w0.x; wT[1][hcol]=w0.y; wT[2][hcol]=w0.z; wT[3][hcol]=w0.w;
    wT[4][hcol]=w1.x; wT[5][hcol]=w1.y; wT[6][hcol]=w1.z; wT[7][hcol]=w1.w;
  }
  if (tid < 16) idxs[tid] = idx[blockIdx.x*16 + tid];
  __syncthreads();
  if (tid < 128){ int tk = tid>>3, cd = tid&7; cbs[tk][cd] = cb[(size_t)idxs[tk]*8 + cd]; }
  __syncthreads();
  float bb[4];
  #pragma unroll
  for (int j=0;j<4;j++) bb[j] = bo[j*256+tid];
  for (int tk=0;tk<16;tk++){
    const size_t m = (size_t)blockIdx.x*16 + tk;
    float c0=cbs[tk][0], c1=cbs[tk][1], c2=cbs[tk][2], c3=cbs[tk][3];
    float c4=cbs[tk][4], c5=cbs[tk][5], c6=cbs[tk][6], c7=cbs[tk][7];
    #pragma unroll
    for (int j=0;j<4;j++){
      int hcol = j*256 + tid;
      float v = bb[j];
      v = fmaf(c0, wT[0][hcol], v); v = fmaf(c1, wT[1][hcol], v);
      v = fmaf(c2, wT[2][hcol], v); v = fmaf(c3, wT[3][hcol], v);
      v = fmaf(c4, wT[4][hcol], v); v = fmaf(c5, wT[5][hcol], v);
      v = fmaf(c6, wT[6][hcol], v); v = fmaf(c7, wT[7][hcol], v);
      outq[m*1024 + hcol] = v;
    }
  }
}

// ---------------- host ----------------

extern "C" void kernel_launch(void* const* d_in, const int* in_sizes, int n_in,
                              void* d_out, int out_size, void* d_ws, size_t ws_size,
                              hipStream_t stream) {
  (void)in_sizes; (void)n_in; (void)out_size;
  const float* x   = (const float*)d_in[0];
  const float* eww = (const float*)d_in[1];
  const float* ewb = (const float*)d_in[2];
  const float* ng  = (const float*)d_in[3];
  const float* nb  = (const float*)d_in[4];
  const float* dww = (const float*)d_in[5];
  const float* dwb = (const float*)d_in[6];
  const float* lng = (const float*)d_in[7];
  const float* lnb = (const float*)d_in[8];
  const float* w1  = (const float*)d_in[9];
  const float* b1  = (const float*)d_in[10];
  const float* w2  = (const float*)d_in[11];
  const float* b2  = (const float*)d_in[12];
  const float* gma = (const float*)d_in[13];
  const float* fg  = (const float*)d_in[14];
  const float* fb  = (const float*)d_in[15];
  const float* ow  = (const float*)d_in[16];
  const float* ob  = (const float*)d_in[17];
  const float* viw = (const float*)d_in[18];
  const float* vib = (const float*)d_in[19];
  const float* cb  = (const float*)d_in[20];
  const float* vow = (const float*)d_in[21];
  const float* vob = (const float*)d_in[22];
  float* out = (float*)d_out;

  // base workspace layout (f32 units), 32,112,640 f = 122.5 MiB (r13):
  float* ws = (float*)d_ws;
  float* wreg = ws;
  _Float16* wkh = (_Float16*)wreg;
  _Float16* wkl = wkh + 2752512;
  _Float16* w1h = (_Float16*)wreg;
  _Float16* w1l = w1h + 786432;
  _Float16* w2h = w1h + 1572864;
  _Float16* w2l = w1h + 2359296;
  float* zn  = wreg + 1048576;
  float* cbn = wreg + 1179648;
  int*  idxb = (int*)(wreg + 1245184);
  float* cw  = wreg + 1261568;
  float* cbias = wreg + 1264640;
  float* h   = ws + 2752512;
  float* ylreg = ws + 9043968;
  float* yf32 = ylreg;
  _Float16* ylh = (_Float16*)ylreg;
  _Float16* yll = ylh + 6291456;
  float* y1reg = ws + 15335424;
  _Float16* xh  = (_Float16*)y1reg;
  _Float16* xl  = xh + 16777216;
  _Float16* y1h = (_Float16*)y1reg;
  _Float16* y1l = y1h + 16777216;

  // optional big layout: all-layer weight splits appended after base (72 MB)
  const bool big = ws_size >= (size_t)203948032;
  _Float16* w1hA = (_Float16*)(ws + 32112640);
  _Float16* w1lA = w1hA + 9437184;
  _Float16* w2hA = w1lA + 9437184;
  _Float16* w2lA = w2hA + 9437184;

  // prep: wk splits + x splits (+ all-layer w splits if space); embed -> yf32; LN -> h
  prep_wk_split<<<dim3(1536), dim3(256), 0, stream>>>(eww, wkh, wkl);
  split_one<<<dim3(16384), dim3(256), 0, stream>>>(x, xh, xl, 4194304);
  if (big)
    split_pair_all<<<dim3(768,12), dim3(256), 0, stream>>>(w1, w2, w1hA, w1lA, w2hA, w2lA);
  embed_f16<<<dim3(6,128), dim3(256), 0, stream>>>(xh, xl, wkh, wkl, ewb, yf32);
  ln_wave<false,false><<<dim3(4096), dim3(256), 0, stream>>>(
      yf32, nullptr, nullptr, ng, nb, h, nullptr, nullptr);

  // 12 ConvNeXt blocks
  for (int i = 0; i < 12; ++i){
    const _Float16 *l1h, *l1l, *l2h, *l2l;
    if (big){
      l1h = w1hA + (size_t)i*786432; l1l = w1lA + (size_t)i*786432;
      l2h = w2hA + (size_t)i*786432; l2l = w2lA + (size_t)i*786432;
    } else {
      split_pair<<<dim3(768), dim3(256), 0, stream>>>(
          w1 + (size_t)i*786432, w2 + (size_t)i*786432, w1h, w1l, w2h, w2l, 196608);
      l1h = w1h; l1l = w1l; l2h = w2h; l2l = w2l;
    }
    ln_wave<true,true><<<dim3(4096), dim3(256), 0, stream>>>(
        h, dww + (size_t)i*2688, dwb + (size_t)i*384,
        lng + (size_t)i*384, lnb + (size_t)i*384, nullptr, ylh, yll);
    for (int ic = 0; ic < 2; ++ic){
      // y1 = gelu(y @ w1_chunk^T + b1_chunk): M=16384, N=1024, K=384
      gemm_t<1><<<dim3(8,64), dim3(512), 0, stream>>>(
          ylh, yll, 384,
          l1h + (size_t)ic*393216, l1l + (size_t)ic*393216, 384,
          b1 + (size_t)i*2048 + (size_t)ic*1024,
          y1h, y1l, 1024, 384);
      // h += gamma * (y1 @ w2_chunk^T + b2(once)): M=16384, N=384, K=1024
      gemm_s<64,2><<<dim3(6,128), dim3(256), 0, stream>>>(
          y1h, y1l, 1024,
          l2h + (size_t)ic*1024, l2l + (size_t)ic*1024, 2048,
          (ic == 0) ? (b2 + (size_t)i*384) : nullptr,
          gma + (size_t)i*384,
          h, nullptr, nullptr, 384, 1024);
    }
  }

  // VQ: prep (cw fold + cbn), fused final-LN + z_e (h read once), argmax, out-proj
  prep_vq<<<dim3(44), dim3(256), 0, stream>>>(viw, ow, vib, ob, cb, cw, cbias, cbn);
  ln_vq<<<dim3(4096), dim3(256), 0, stream>>>(h, fg, fb, cw, cbias, zn);
  vq_argmax<<<dim3(512), dim3(256), 0, stream>>>(zn, cbn, idxb, out);
  vq_out_kernel<<<dim3(1024), dim3(256), 0, stream>>>(idxb, cb, vow, vob, out + 16384);
}